// Round 4
// baseline (175.120 us; speedup 1.0000x reference)
//
#include <hip/hip_runtime.h>
#include <stdint.h>

#define NN 100000
#define EE 600000
#define DD 128

typedef _Float16 half8 __attribute__((ext_vector_type(8)));
typedef _Float16 h2 __attribute__((ext_vector_type(2)));
typedef float f32x4 __attribute__((ext_vector_type(4)));

__device__ __forceinline__ float pack_h2(float a, float b) {
    h2 h; h.x = (_Float16)a; h.y = (_Float16)b;
    return __builtin_bit_cast(float, h);
}

// ---------------------------------------------------------------------------
// Prep: W1/W2 -> single-f16 MFMA B-fragment linear order:
// frag f = (kt*8 + nt), element [f*64 + lane]*8 + j,
// where k = kt*32 + (lane>>4)*8 + j, d = nt*16 + (lane&15).
// Also zeroes counts+cursor (2*NN ints) when zero_base != nullptr.
// ---------------------------------------------------------------------------
__global__ __launch_bounds__(256)
void prep_weights(const float* __restrict__ W1, const float* __restrict__ W2,
                  _Float16* __restrict__ w1h, _Float16* __restrict__ w2h,
                  int* __restrict__ zero_base)
{
    int t = blockIdx.x * 256 + threadIdx.x;
    if (zero_base && t < 2 * NN) zero_base[t] = 0;
    if (t >= 2 * DD * DD) return;
    int which = t >> 14;           // 0 -> W1, 1 -> W2
    int idx = t & (DD * DD - 1);
    int k = idx >> 7;
    int d = idx & 127;
    float wv = (which ? W2 : W1)[k * DD + d];
    int kt = k >> 5, kr = k & 31;
    int grp = kr >> 3, j = kr & 7;
    int nt = d >> 4, cc = d & 15;
    int lane = grp * 16 + cc;
    int off = ((kt * 8 + nt) * 64 + lane) * 8 + j;
    (which ? w2h : w1h)[off] = (_Float16)wv;
}

// ---------------------------------------------------------------------------
// CSR build step 1: histogram of destination nodes (int atomics).
// ---------------------------------------------------------------------------
__global__ __launch_bounds__(256)
void hist_kernel(const int* __restrict__ ei, int* __restrict__ counts)
{
    int e = blockIdx.x * 256 + threadIdx.x;
    if (e < EE) atomicAdd(&counts[ei[EE + e]], 1);
}

// ---------------------------------------------------------------------------
// CSR build step 2a: exclusive scan, 1024 elems/block (256 thr x int4).
// ---------------------------------------------------------------------------
__global__ __launch_bounds__(256)
void scan_blocks(const int* __restrict__ counts, int* __restrict__ startv,
                 int* __restrict__ bsum)
{
    const int t = threadIdx.x;
    const int idx = blockIdx.x * 1024 + t * 4;
    int4 v = {0, 0, 0, 0};
    if (idx < NN) v = *(const int4*)(counts + idx);     // NN % 4 == 0
    int s1 = v.x + v.y, s2 = s1 + v.z, s3 = s2 + v.w;
    const int lane = t & 63;
    int q = s3;
#pragma unroll
    for (int off = 1; off < 64; off <<= 1) {
        int u = __shfl_up(q, off, 64);
        if (lane >= off) q += u;
    }
    __shared__ int wsum[4];
    if (lane == 63) wsum[t >> 6] = q;
    __syncthreads();
    const int w = t >> 6;
    int pre = 0;
    if (w > 0) pre += wsum[0];
    if (w > 1) pre += wsum[1];
    if (w > 2) pre += wsum[2];
    const int excl = (q - s3) + pre;
    if (idx < NN) {
        int4 o = {excl, excl + v.x, excl + s1, excl + s2};
        *(int4*)(startv + idx) = o;
    }
    __syncthreads();
    if (t == 0) bsum[blockIdx.x] = wsum[0] + wsum[1] + wsum[2] + wsum[3];
}

// ---------------------------------------------------------------------------
// CSR build step 2b: exclusive scan of the block sums (single block).
// ---------------------------------------------------------------------------
__global__ __launch_bounds__(128)
void scan_top(const int* __restrict__ bsum, int* __restrict__ boff)
{
    __shared__ int sm[128];
    const int t = threadIdx.x;
    const int NB = (NN + 1023) / 1024;
    int v = (t < NB) ? bsum[t] : 0;
    sm[t] = v;
    __syncthreads();
#pragma unroll
    for (int off = 1; off < 128; off <<= 1) {
        int u = (t >= off) ? sm[t - off] : 0;
        __syncthreads();
        sm[t] += u;
        __syncthreads();
    }
    boff[t] = sm[t] - v;
}

// ---------------------------------------------------------------------------
// CSR build step 3: scatter 16B records {src, h2 ea01, h2 ea23, h2 ea45}.
// ---------------------------------------------------------------------------
__global__ __launch_bounds__(256)
void scatter_rec(const int* __restrict__ ei, const float* __restrict__ ea,
                 const int* __restrict__ start, const int* __restrict__ boff,
                 int* __restrict__ cursor, float* __restrict__ rec)
{
    int e = blockIdx.x * 256 + threadIdx.x;
    if (e >= EE) return;
    int dst = ei[EE + e];
    int src = ei[e];
    int pos = start[dst] + boff[dst >> 10] + atomicAdd(&cursor[dst], 1);
    const float2* eap = (const float2*)(ea + e * 6);
    float2 e01 = eap[0];
    float2 e23 = eap[1];
    float2 e45 = eap[2];
    float4 r;
    r.x = __int_as_float(src);
    r.y = pack_h2(e01.x, e01.y);
    r.z = pack_h2(e23.x, e23.y);
    r.w = pack_h2(e45.x, e45.y);
    *(float4*)(rec + (size_t)pos * 4) = r;
}

// ---------------------------------------------------------------------------
// Aggregation: persistent waves, 64 lanes per node (no divergence), each wave
// owns a contiguous node range -> sequential rec reads. h0 = (1+eps)x + agg.
// H0F16: write f16 h0 to h0h; else f32 to h0f.
// ---------------------------------------------------------------------------
#define NWAVE 8192
template<bool H0F16>
__global__ __launch_bounds__(256)
void agg_pers(const float* __restrict__ x, const float* __restrict__ rec,
              const float* __restrict__ We, const float* __restrict__ be,
              const int* __restrict__ start, const int* __restrict__ boff,
              const int* __restrict__ counts, const float* __restrict__ epsp,
              float* __restrict__ h0f, _Float16* __restrict__ h0h)
{
    const int w = blockIdx.x * 4 + (threadIdx.x >> 6);
    const int lane = threadIdx.x & 63;
    const int d0 = lane * 2;
    float2 w0 = *(const float2*)(We + 0 * DD + d0);
    float2 w1 = *(const float2*)(We + 1 * DD + d0);
    float2 w2 = *(const float2*)(We + 2 * DD + d0);
    float2 w3 = *(const float2*)(We + 3 * DD + d0);
    float2 w4 = *(const float2*)(We + 4 * DD + d0);
    float2 w5 = *(const float2*)(We + 5 * DD + d0);
    float2 bb = *(const float2*)(be + d0);
    const float sc = 1.0f + epsp[0];
    const int n0 = (int)(((long long)w * NN) >> 13);
    const int n1 = (int)(((long long)(w + 1) * NN) >> 13);

#define EDGE_ACC2(R, XJ, WGT)                                                   \
    do {                                                                        \
        h2 p01 = __builtin_bit_cast(h2, (R).y);                                 \
        h2 p23 = __builtin_bit_cast(h2, (R).z);                                 \
        h2 p45 = __builtin_bit_cast(h2, (R).w);                                 \
        float f0 = (float)p01.x, f1 = (float)p01.y;                             \
        float f2 = (float)p23.x, f3 = (float)p23.y;                             \
        float f4 = (float)p45.x, f5 = (float)p45.y;                             \
        float tx = (XJ).x + bb.x, ty = (XJ).y + bb.y;                           \
        tx = fmaf(f0, w0.x, tx); ty = fmaf(f0, w0.y, ty);                       \
        tx = fmaf(f1, w1.x, tx); ty = fmaf(f1, w1.y, ty);                       \
        tx = fmaf(f2, w2.x, tx); ty = fmaf(f2, w2.y, ty);                       \
        tx = fmaf(f3, w3.x, tx); ty = fmaf(f3, w3.y, ty);                       \
        tx = fmaf(f4, w4.x, tx); ty = fmaf(f4, w4.y, ty);                       \
        tx = fmaf(f5, w5.x, tx); ty = fmaf(f5, w5.y, ty);                       \
        ax = fmaf((WGT), fmaxf(tx, 0.f), ax);                                   \
        ay = fmaf((WGT), fmaxf(ty, 0.f), ay);                                   \
    } while (0)

    for (int n = n0; n < n1; ++n) {
        const int begin = start[n] + boff[n >> 10];
        const int cnt = counts[n];
        const float4* rp = (const float4*)(rec + (size_t)begin * 4);
        float ax = 0.f, ay = 0.f;
        for (int i = 0; i < cnt; i += 4) {
            const int rem = cnt - i;
            const int ia = i;
            const int ib = i + (rem > 1 ? 1 : 0);
            const int ic = i + (rem > 2 ? 2 : 0);
            const int id = i + (rem > 3 ? 3 : 0);
            float4 ra = rp[ia], rb = rp[ib], rc = rp[ic], rd = rp[id];
            int sa = __float_as_int(ra.x), sb = __float_as_int(rb.x),
                sc2 = __float_as_int(rc.x), sd = __float_as_int(rd.x);
            float2 xa = *(const float2*)(x + (size_t)sa * DD + d0);
            float2 xb = *(const float2*)(x + (size_t)sb * DD + d0);
            float2 xc = *(const float2*)(x + (size_t)sc2 * DD + d0);
            float2 xd = *(const float2*)(x + (size_t)sd * DD + d0);
            const float wb2 = rem > 1 ? 1.f : 0.f;
            const float wc2 = rem > 2 ? 1.f : 0.f;
            const float wd2 = rem > 3 ? 1.f : 0.f;
            EDGE_ACC2(ra, xa, 1.f);
            EDGE_ACC2(rb, xb, wb2);
            EDGE_ACC2(rc, xc, wc2);
            EDGE_ACC2(rd, xd, wd2);
        }
        float2 xn = *(const float2*)(x + (size_t)n * DD + d0);
        float hx = sc * xn.x + ax;
        float hy = sc * xn.y + ay;
        if (H0F16) {
            h2 p; p.x = (_Float16)hx; p.y = (_Float16)hy;
            *(h2*)(h0h + (size_t)n * DD + d0) = p;
        } else {
            float2 o; o.x = hx; o.y = hy;
            *(float2*)(h0f + (size_t)n * DD + d0) = o;
        }
    }
#undef EDGE_ACC2
}

// ---------------------------------------------------------------------------
// Tier-C fallback: atomic scatter (f32 agg into d_out).
// ---------------------------------------------------------------------------
__global__ __launch_bounds__(256)
void edge_kernel(const float* __restrict__ x, const int* __restrict__ ei,
                 const float* __restrict__ ea, const float* __restrict__ We,
                 const float* __restrict__ be, float* agg)
{
    int tid = blockIdx.x * 256 + threadIdx.x;
    int d0 = (tid & 31) * 4;
    float4 w0 = *(const float4*)(We + 0 * DD + d0);
    float4 w1 = *(const float4*)(We + 1 * DD + d0);
    float4 w2 = *(const float4*)(We + 2 * DD + d0);
    float4 w3 = *(const float4*)(We + 3 * DD + d0);
    float4 w4 = *(const float4*)(We + 4 * DD + d0);
    float4 w5 = *(const float4*)(We + 5 * DD + d0);
    float4 bb = *(const float4*)(be + d0);
    int estride = (gridDim.x * 256) >> 5;
    for (int e = tid >> 5; e < EE; e += estride) {
        int src = ei[e];
        int dst = ei[EE + e];
        const float2* eap = (const float2*)(ea + e * 6);
        float2 e01 = eap[0];
        float2 e23 = eap[1];
        float2 e45 = eap[2];
        float4 xj = *(const float4*)(x + (size_t)src * DD + d0);
        float mx = xj.x + bb.x + e01.x*w0.x + e01.y*w1.x + e23.x*w2.x + e23.y*w3.x + e45.x*w4.x + e45.y*w5.x;
        float my = xj.y + bb.y + e01.x*w0.y + e01.y*w1.y + e23.x*w2.y + e23.y*w3.y + e45.x*w4.y + e45.y*w5.y;
        float mz = xj.z + bb.z + e01.x*w0.z + e01.y*w1.z + e23.x*w2.z + e23.y*w3.z + e45.x*w4.z + e45.y*w5.z;
        float mw = xj.w + bb.w + e01.x*w0.w + e01.y*w1.w + e23.x*w2.w + e23.y*w3.w + e45.x*w4.w + e45.y*w5.w;
        float* ap = agg + (size_t)dst * DD + d0;
        atomicAdd(ap + 0, fmaxf(mx, 0.f));
        atomicAdd(ap + 1, fmaxf(my, 0.f));
        atomicAdd(ap + 2, fmaxf(mz, 0.f));
        atomicAdd(ap + 3, fmaxf(mw, 0.f));
    }
}

// ---------------------------------------------------------------------------
// Node phase: h1 = relu(h0@W1+b1); h2 = h1@W2+b2; out = relu(LN(h2)*g+b).
// Single-f16 MFMA (1 per k/n tile). One wave = 2 tiles x 16 rows x 128 cols.
// MODE 0: h0 is f16 (ws). MODE 1: h0 is f32 (d_out, in-place).
// MODE 2: h0 = (1+eps)x + agg computed in-kernel (tier C).
// ---------------------------------------------------------------------------
template<int MODE>
__global__ __launch_bounds__(256)
void node2(const void* __restrict__ h0p, const float* __restrict__ xp,
           const _Float16* __restrict__ w1h, const _Float16* __restrict__ w2h,
           const float* __restrict__ b1, const float* __restrict__ b2,
           const float* __restrict__ gamma, const float* __restrict__ beta,
           const float* __restrict__ epsp, float* __restrict__ out)
{
    __shared__ _Float16 h1buf[4][16 * 128];   // 16 KiB, 4 KiB per wave
    const int wv = threadIdx.x >> 6;
    const int l  = threadIdx.x & 63;
    const int lm = l & 15;
    const int lg = l >> 4;
    const int rbase = blockIdx.x * 128 + wv * 32;

    float gam[8], bet[8];
#pragma unroll
    for (int nt = 0; nt < 8; ++nt) {
        gam[nt] = gamma[nt * 16 + lm];
        bet[nt] = beta[nt * 16 + lm];
    }

    for (int t = 0; t < 2; ++t) {
        const int r0 = rbase + t * 16;
        int arow = r0 + lm;
        if (arow >= NN) arow = NN - 1;

        // ---- A1 fragments (row = lm, k = kt*32 + lg*8 + j)
        half8 a1[4];
#pragma unroll
        for (int kt = 0; kt < 4; ++kt) {
            const int kb = kt * 32 + lg * 8;
            if constexpr (MODE == 0) {
                a1[kt] = *(const half8*)((const _Float16*)h0p + (size_t)arow * DD + kb);
            } else {
                const float4* hp = (const float4*)((const float*)h0p + (size_t)arow * DD + kb);
                float4 p0 = hp[0], p1 = hp[1];
                float v[8];
                if constexpr (MODE == 2) {
                    const float scale = 1.0f + epsp[0];
                    const float4* xr = (const float4*)(xp + (size_t)arow * DD + kb);
                    float4 x0 = xr[0], x1 = xr[1];
                    v[0]=x0.x*scale+p0.x; v[1]=x0.y*scale+p0.y; v[2]=x0.z*scale+p0.z; v[3]=x0.w*scale+p0.w;
                    v[4]=x1.x*scale+p1.x; v[5]=x1.y*scale+p1.y; v[6]=x1.z*scale+p1.z; v[7]=x1.w*scale+p1.w;
                } else {
                    v[0]=p0.x; v[1]=p0.y; v[2]=p0.z; v[3]=p0.w;
                    v[4]=p1.x; v[5]=p1.y; v[6]=p1.z; v[7]=p1.w;
                }
#pragma unroll
                for (int j = 0; j < 8; ++j) a1[kt][j] = (_Float16)v[j];
            }
        }

        // ---- GEMM1
        f32x4 acc[8];
#pragma unroll
        for (int nt = 0; nt < 8; ++nt) { acc[nt][0]=0.f; acc[nt][1]=0.f; acc[nt][2]=0.f; acc[nt][3]=0.f; }
#pragma unroll
        for (int kt = 0; kt < 4; ++kt) {
#pragma unroll
            for (int nt = 0; nt < 8; ++nt) {
                half8 bh = *(const half8*)(w1h + ((size_t)((kt * 8 + nt) * 64 + l)) * 8);
                acc[nt] = __builtin_amdgcn_mfma_f32_16x16x32_f16(a1[kt], bh, acc[nt], 0, 0, 0);
            }
        }

        // ---- epilogue 1: relu(+b1) -> f16 -> LDS (XOR swizzle by row)
        _Float16* hb = h1buf[wv];
#pragma unroll
        for (int nt = 0; nt < 8; ++nt) {
            const int col = nt * 16 + lm;
            const float bias = b1[col];
#pragma unroll
            for (int q = 0; q < 4; ++q) {
                const int row = lg * 4 + q;
                float v1 = fmaxf(acc[nt][q] + bias, 0.f);
                hb[row * 128 + (col ^ ((row & 7) << 4))] = (_Float16)v1;
            }
        }
        __syncthreads();

        // ---- A2 fragments from LDS (same swizzle; 8 contiguous f16 = 16B)
        half8 a2[4];
        {
            const int sw = (lm & 7) << 4;
            const _Float16* rowp = hb + lm * 128;
#pragma unroll
            for (int kt = 0; kt < 4; ++kt) {
                const int kb = kt * 32 + lg * 8;
                a2[kt] = *(const half8*)(rowp + (kb ^ sw));
            }
        }

        // ---- GEMM2
        f32x4 acc2[8];
#pragma unroll
        for (int nt = 0; nt < 8; ++nt) { acc2[nt][0]=0.f; acc2[nt][1]=0.f; acc2[nt][2]=0.f; acc2[nt][3]=0.f; }
#pragma unroll
        for (int kt = 0; kt < 4; ++kt) {
#pragma unroll
            for (int nt = 0; nt < 8; ++nt) {
                half8 bh = *(const half8*)(w2h + ((size_t)((kt * 8 + nt) * 64 + l)) * 8);
                acc2[nt] = __builtin_amdgcn_mfma_f32_16x16x32_f16(a2[kt], bh, acc2[nt], 0, 0, 0);
            }
        }

        // ---- epilogue 2: +b2, LayerNorm per row, relu, store
        float vv[8][4];
        float sums[4] = {0,0,0,0}, sqs[4] = {0,0,0,0};
#pragma unroll
        for (int nt = 0; nt < 8; ++nt) {
            const int col = nt * 16 + lm;
            const float bias = b2[col];
#pragma unroll
            for (int q = 0; q < 4; ++q) {
                float v2 = acc2[nt][q] + bias;
                vv[nt][q] = v2;
                sums[q] += v2;
                sqs[q]  += v2 * v2;
            }
        }
#pragma unroll
        for (int m = 1; m < 16; m <<= 1) {
#pragma unroll
            for (int q = 0; q < 4; ++q) {
                sums[q] += __shfl_xor(sums[q], m, 64);
                sqs[q]  += __shfl_xor(sqs[q],  m, 64);
            }
        }
#pragma unroll
        for (int q = 0; q < 4; ++q) {
            const int grow = r0 + lg * 4 + q;
            if (grow < NN) {
                const float mu  = sums[q] * (1.f / 128.f);
                const float var = sqs[q] * (1.f / 128.f) - mu * mu;
                const float rs  = rsqrtf(var + 1e-5f);
#pragma unroll
                for (int nt = 0; nt < 8; ++nt) {
                    out[(size_t)grow * DD + nt * 16 + lm] =
                        fmaxf((vv[nt][q] - mu) * rs * gam[nt] + bet[nt], 0.f);
                }
            }
        }
        __syncthreads();
    }
}

extern "C" void kernel_launch(void* const* d_in, const int* in_sizes, int n_in,
                              void* d_out, int out_size, void* d_ws, size_t ws_size,
                              hipStream_t stream) {
    (void)in_sizes; (void)n_in; (void)out_size;
    const float* x     = (const float*)d_in[0];
    const int*   ei    = (const int*)d_in[1];
    const float* ea    = (const float*)d_in[2];
    const float* We    = (const float*)d_in[4];
    const float* be    = (const float*)d_in[5];
    const float* epsp  = (const float*)d_in[6];
    const float* W1    = (const float*)d_in[7];
    const float* b1    = (const float*)d_in[8];
    const float* W2    = (const float*)d_in[9];
    const float* b2    = (const float*)d_in[10];
    const float* gamma = (const float*)d_in[11];
    const float* beta  = (const float*)d_in[12];
    float* out = (float*)d_out;

    // ---- workspace layout (16B-aligned)
    char* ws = (char*)d_ws;
    _Float16* w1h = (_Float16*)ws;                            // 32 KiB
    _Float16* w2h = w1h + DD * DD;                            // 32 KiB
    size_t off = 2 * (size_t)DD * DD * sizeof(_Float16);      // 65536
    int* counts = (int*)(ws + off);   off += (size_t)NN * 4;
    int* cursor = (int*)(ws + off);   off += (size_t)NN * 4;
    int* start  = (int*)(ws + off);   off += (size_t)NN * 4;
    int* bsum   = (int*)(ws + off);   off += 512;
    int* boff   = (int*)(ws + off);   off += 512;
    float* rec  = (float*)(ws + off); off += (size_t)EE * 16;
    const size_t need1 = off;                                  // ~10.9 MB
    _Float16* h0h = (_Float16*)(ws + off); off += (size_t)NN * DD * sizeof(_Float16);
    const size_t need0 = off;                                  // ~36.5 MB

    const int NBLK = (NN + 1023) / 1024;
    const int node_blocks = (NN + 127) / 128;

    if (ws_size >= need1) {
        const bool f16h0 = (ws_size >= need0);
        prep_weights<<<(2 * NN + 255) / 256, 256, 0, stream>>>(W1, W2, w1h, w2h, counts);
        hist_kernel<<<(EE + 255) / 256, 256, 0, stream>>>(ei, counts);
        scan_blocks<<<NBLK, 256, 0, stream>>>(counts, start, bsum);
        scan_top<<<1, 128, 0, stream>>>(bsum, boff);
        scatter_rec<<<(EE + 255) / 256, 256, 0, stream>>>(ei, ea, start, boff, cursor, rec);
        if (f16h0) {
            agg_pers<true><<<NWAVE / 4, 256, 0, stream>>>(x, rec, We, be, start, boff,
                                                          counts, epsp, nullptr, h0h);
            node2<0><<<node_blocks, 256, 0, stream>>>(h0h, x, w1h, w2h, b1, b2,
                                                      gamma, beta, epsp, out);
        } else {
            agg_pers<false><<<NWAVE / 4, 256, 0, stream>>>(x, rec, We, be, start, boff,
                                                           counts, epsp, out, nullptr);
            node2<1><<<node_blocks, 256, 0, stream>>>(out, x, w1h, w2h, b1, b2,
                                                      gamma, beta, epsp, out);
        }
    } else {
        // Tier C: atomic scatter into d_out, node computes h0 in-kernel.
        hipMemsetAsync(d_out, 0, (size_t)NN * DD * sizeof(float), stream);
        prep_weights<<<(2 * DD * DD + 255) / 256, 256, 0, stream>>>(W1, W2, w1h, w2h, nullptr);
        edge_kernel<<<2048, 256, 0, stream>>>(x, ei, ea, We, be, out);
        node2<2><<<node_blocks, 256, 0, stream>>>(out, x, w1h, w2h, b1, b2,
                                                  gamma, beta, epsp, out);
    }
}